// Round 7
// baseline (195.608 us; speedup 1.0000x reference)
//
#include <hip/hip_runtime.h>
#include <math.h>

constexpr int B_ = 128;
constexpr int N_ = 512;
constexpr int K_ = 510;     // number of diagonals = N-2
constexpr int SPLIT = 16;   // blocks per batch
constexpr int PAD = 520;    // LDS floats per staged row (512 + 8 pad)

typedef float float4v __attribute__((ext_vector_type(4)));

// Kernel 1 (R7): ALIGNED dwordx4 global reads through LDS.
// Every prior version used per-lane dword loads at 4B-misaligned,
// row-fragmented offsets and pinned at ~2 TB/s; this tests the
// request-granularity hypothesis: stage each needed row segment
// (rounded down to a 64-float boundary -> all loads 16B-aligned) into
// LDS, then consume diagonals from LDS (consecutive lanes -> consecutive
// banks, conflict-free). Work pairing unchanged: block s owns rows
// [16s,16s+16) (stage A) and [496-16s,512-16s) (stage B); thread t owns
// diagonals k_a = t and k_b = 511-t, register accumulation.
__global__ __launch_bounds__(256) void diag_partial_kernel(
    const float* __restrict__ in, float* __restrict__ ws) {
  __shared__ float L[16 * PAD];          // 33,280 B -> 4 blocks/CU
  const int b = blockIdx.x >> 4;
  const int s = blockIdx.x & 15;
  const int t = threadIdx.x;             // t in [0,256)
  const float* base = in + (size_t)b * N_ * N_;

  float Sa = 0.f, Qa = 0.f, Sb = 0.f, Qb = 0.f;

  // ---- Stage A: rows [16s, 16s+16), p in [0,256) ----
  {
    const int rA = 16 * s;
    const int q = t & 127;               // float4 index within row
    const int half = t >> 7;             // 2 rows per pass
#pragma unroll
    for (int j = 0; j < 8; ++j) {
      const int i = 2 * j + half;
      const int p = rA + i;
      const int c0 = (p + 1) & ~63;      // aligned segment start (floats)
      const int col = 4 * q;
      if (col >= c0) {
        const float4v v = *(const float4v*)(base + (size_t)p * N_ + col);
        *(float4v*)&L[i * PAD + col] = v;
      }
    }
    __syncthreads();
#pragma unroll
    for (int i = 0; i < 16; ++i) {
      const int p = rA + i;
      // a-stream: col = p+1+t <= 511 always in stage A, >= c0 always.
      const float xa = L[i * PAD + (p + 1 + t)];
      Sa += xa; Qa = fmaf(xa, xa, Qa);
      // b-stream: valid iff t > p; clamp OOB lanes inside the row, zero after.
      const int cb = p + 512 - t;
      float xb = L[i * PAD + (cb < PAD ? cb : PAD - 1)];
      xb = (t > p) ? xb : 0.f;
      Sb += xb; Qb = fmaf(xb, xb, Qb);
    }
    __syncthreads();                     // B-load overwrites L
  }

  // ---- Stage B: rows [496-16s, 512-16s), p in [256,512): a-stream only ----
  {
    const int rB = (N_ - 16) - 16 * s;
    const int q = t & 63;
    const int quarter = t >> 6;          // 4 rows per pass
#pragma unroll
    for (int j = 0; j < 4; ++j) {
      const int i = 4 * j + quarter;
      const int p = rB + i;
      const int c0 = (p + 1) & ~63;      // >= 256 here
      const int col = 256 + 4 * q;
      if (col >= c0) {
        const float4v v = *(const float4v*)(base + (size_t)p * N_ + col);
        *(float4v*)&L[i * PAD + col] = v;
      }
    }
    __syncthreads();
#pragma unroll
    for (int i = 0; i < 16; ++i) {
      const int p = rB + i;
      const int ca = p + 1 + t;
      float xa = L[i * PAD + (ca < PAD ? ca : PAD - 1)];
      xa = (t < N_ - 1 - p) ? xa : 0.f;  // valid iff t < 511-p
      Sa += xa; Qa = fmaf(xa, xa, Qa);
    }
  }

  float* w = ws + (size_t)blockIdx.x * (2 * N_);  // blockIdx.x == b*SPLIT+s
  // thread t writes k=t and k=511-t (disjoint slots; finalize's t<K_ guard
  // drops the nonexistent k=510,511 b-slots for t=0,1)
  w[t] = Sa;
  w[t + N_] = Qa;
  w[(N_ - 1) - t] = Sb;
  w[(N_ - 1) - t + N_] = Qb;
}

// Kernel 2: combine partials (fully-unrolled constant-trip loop -> 32
// independent loads in flight), compute scaled = sqrt(var)*len/5 per k,
// reduce mean over k, write both tuple outputs.
__global__ __launch_bounds__(512) void finalize_kernel(
    const float* __restrict__ ws, float* __restrict__ out) {
  __shared__ float red[8];
  const int b = blockIdx.x;
  const int t = threadIdx.x;
  float Ssum = 0.0f, Qsum = 0.0f;
#pragma unroll
  for (int s = 0; s < SPLIT; ++s) {
    const float* w = ws + (size_t)(b * SPLIT + s) * (2 * N_);
    Ssum += w[t];
    Qsum += w[t + N_];
  }
  float scaled = 0.0f;
  if (t < K_) {
    float len = (float)(N_ - 1 - t);
    float mean = Ssum / len;
    float var = (Qsum - Ssum * mean) / (len - 1.0f);
    var = fmaxf(var, 0.0f);        // guard tiny negative from rounding
    scaled = sqrtf(var) * len * 0.2f;
  }
  // wave-64 reduction
  for (int off = 32; off > 0; off >>= 1)
    scaled += __shfl_down(scaled, off, 64);
  const int wid = t >> 6;
  if ((t & 63) == 0) red[wid] = scaled;
  __syncthreads();
  if (t == 0) {
    float tot = 0.0f;
    for (int i = 0; i < 8; ++i) tot += red[i];
    float loss = tot / (float)K_;
    out[b] = loss;        // output 0: loss
    out[B_ + b] = loss;   // output 1: stop_gradient(loss) == loss
  }
}

extern "C" void kernel_launch(void* const* d_in, const int* in_sizes, int n_in,
                              void* d_out, int out_size, void* d_ws, size_t ws_size,
                              hipStream_t stream) {
  const float* in = (const float*)d_in[0];
  float* out = (float*)d_out;
  float* ws = (float*)d_ws;
  // 2048 blocks of 256 threads; ws use: 8 MB.
  diag_partial_kernel<<<B_ * SPLIT, 256, 0, stream>>>(in, ws);
  finalize_kernel<<<B_, 512, 0, stream>>>(ws, out);
}

// Round 8
// 180.117 us; speedup vs baseline: 1.0860x; 1.0860x over previous
//
#include <hip/hip_runtime.h>
#include <math.h>

constexpr int B_ = 128;
constexpr int N_ = 512;
constexpr int K_ = 510;     // number of diagonals = N-2
constexpr int SPLIT = 16;   // compile-time: lets finalize's s-loop fully unroll

// Kernel 1 (restored R5 best-known config, 178.9 us total):
// thread t owns TWO diagonals: k_a = t (length 511-t) and k_b = 511-t
// (length t). Per-lane work = 511 rows for EVERY thread -> uniform across
// lanes/waves/SIMDs/blocks. Both streams lane-contiguous (one coalesced
// 256B segment per wave). Register-only accumulation, 4-row unroll
// (8 loads in flight/wave). Later experiments (contiguous row chunks R6,
// LDS-staged dwordx4 R7) were neutral-to-negative -> this access pattern
// is at/near the kernel's HBM-latency/BW floor (~15us vs 11us roofline).
__global__ __launch_bounds__(256) void diag_partial_kernel(
    const float* __restrict__ in, float* __restrict__ ws) {
  const int b = blockIdx.x / SPLIT;
  const int s = blockIdx.x % SPLIT;
  const int t = threadIdx.x;            // t in [0,256)
  const float* base = in + (size_t)b * N_ * N_;
  const int la = (N_ - 1) - t;          // rows of diag k_a = t
  const int lb = t;                     // rows of diag k_b = 511-t
  constexpr size_t step = (size_t)SPLIT * (N_ + 1);
  const float* pa = base + (size_t)s * (N_ + 1) + 1 + t;
  const float* pb = base + (size_t)s * (N_ + 1) + (N_ - t);
  float Sa0 = 0.f, Qa0 = 0.f, Sa1 = 0.f, Qa1 = 0.f;
  float Sb0 = 0.f, Qb0 = 0.f, Sb1 = 0.f, Qb1 = 0.f;
  int p = s;
  // la > lb for all t in [0,256), so la bounds the fused loop.
  for (; p + 3 * SPLIT < la; p += 4 * SPLIT) {
    float a0 = pa[0];
    float a1 = pa[step];
    float a2 = pa[2 * step];
    float a3 = pa[3 * step];
    float b0 = 0.f, b1 = 0.f, b2 = 0.f, b3 = 0.f;
    if (p < lb)             b0 = pb[0];
    if (p + SPLIT < lb)     b1 = pb[step];
    if (p + 2 * SPLIT < lb) b2 = pb[2 * step];
    if (p + 3 * SPLIT < lb) b3 = pb[3 * step];
    Sa0 += a0; Qa0 = fmaf(a0, a0, Qa0);
    Sa1 += a1; Qa1 = fmaf(a1, a1, Qa1);
    Sa0 += a2; Qa0 = fmaf(a2, a2, Qa0);
    Sa1 += a3; Qa1 = fmaf(a3, a3, Qa1);
    Sb0 += b0; Qb0 = fmaf(b0, b0, Qb0);
    Sb1 += b1; Qb1 = fmaf(b1, b1, Qb1);
    Sb0 += b2; Qb0 = fmaf(b2, b2, Qb0);
    Sb1 += b3; Qb1 = fmaf(b3, b3, Qb1);
    pa += 4 * step;
    pb += 4 * step;
  }
  for (; p < la; p += SPLIT) {
    float a0 = pa[0];
    Sa0 += a0; Qa0 = fmaf(a0, a0, Qa0);
    if (p < lb) {
      float b0 = pb[0];
      Sb0 += b0; Qb0 = fmaf(b0, b0, Qb0);
    }
    pa += step;
    pb += step;
  }
  float* w = ws + (size_t)blockIdx.x * (2 * N_);  // blockIdx.x == b*SPLIT+s
  // thread t writes k=t and k=511-t (disjoint: [0,256) vs [256,512))
  w[t] = Sa0 + Sa1;
  w[t + N_] = Qa0 + Qa1;
  w[(N_ - 1) - t] = Sb0 + Sb1;
  w[(N_ - 1) - t + N_] = Qb0 + Qb1;
}

// Kernel 2: combine partials (fully-unrolled constant-trip loop -> 32
// independent loads in flight), compute scaled = sqrt(var)*len/5 per k,
// reduce mean over k, write both tuple outputs.
__global__ __launch_bounds__(512) void finalize_kernel(
    const float* __restrict__ ws, float* __restrict__ out) {
  __shared__ float red[8];
  const int b = blockIdx.x;
  const int t = threadIdx.x;
  float Ssum = 0.0f, Qsum = 0.0f;
#pragma unroll
  for (int s = 0; s < SPLIT; ++s) {
    const float* w = ws + (size_t)(b * SPLIT + s) * (2 * N_);
    Ssum += w[t];
    Qsum += w[t + N_];
  }
  float scaled = 0.0f;
  if (t < K_) {
    float len = (float)(N_ - 1 - t);
    float mean = Ssum / len;
    float var = (Qsum - Ssum * mean) / (len - 1.0f);
    var = fmaxf(var, 0.0f);        // guard tiny negative from rounding
    scaled = sqrtf(var) * len * 0.2f;
  }
  // wave-64 reduction
  for (int off = 32; off > 0; off >>= 1)
    scaled += __shfl_down(scaled, off, 64);
  const int wid = t >> 6;
  if ((t & 63) == 0) red[wid] = scaled;
  __syncthreads();
  if (t == 0) {
    float tot = 0.0f;
    for (int i = 0; i < 8; ++i) tot += red[i];
    float loss = tot / (float)K_;
    out[b] = loss;        // output 0: loss
    out[B_ + b] = loss;   // output 1: stop_gradient(loss) == loss
  }
}

extern "C" void kernel_launch(void* const* d_in, const int* in_sizes, int n_in,
                              void* d_out, int out_size, void* d_ws, size_t ws_size,
                              hipStream_t stream) {
  const float* in = (const float*)d_in[0];
  float* out = (float*)d_out;
  float* ws = (float*)d_ws;
  // 2048 blocks of 256 threads -> 8 blocks/CU, 32 waves/CU. ws use: 8 MB.
  diag_partial_kernel<<<B_ * SPLIT, 256, 0, stream>>>(in, ws);
  finalize_kernel<<<B_, 512, 0, stream>>>(ws, out);
}